// Round 1
// baseline (279.669 us; speedup 1.0000x reference)
//
#include <hip/hip_runtime.h>

// ---------- types ----------
typedef _Float16 f16;
typedef _Float16 f16x4 __attribute__((ext_vector_type(4)));
typedef _Float16 f16x8 __attribute__((ext_vector_type(8)));
typedef float    f32x4 __attribute__((ext_vector_type(4)));

#define N_ROWS 100000
#define RT 782            // row tiles of 128 -> 100096 padded rows
#define PAD_ROWS (RT * 128)
#define LDS_STRIDE 40     // 32 f16 + 8 pad (80 B, keeps 16B alignment, spreads banks)

// ws layout (bytes)
#define W1T_OFF 0
#define W1T_BYTES (256 * 256 * 2)
#define W2T_OFF (W1T_OFF + W1T_BYTES)
#define W2T_BYTES (128 * 128 * 2)
#define H1_OFF (W2T_OFF + W2T_BYTES)
#define H1_BYTES (PAD_ROWS * 128 * 2)
#define H2_OFF (H1_OFF + H1_BYTES)

// ---------- prep: combined, transposed f16 weights ----------
// W1T[c][k], c in [0,256): c<128 -> Az1 col c ; c>=128 -> Ah1 col c-128. k in [0,256).
__global__ void prep_w1(const float* __restrict__ wz, const float* __restrict__ wh,
                        f16* __restrict__ W1T) {
    int idx = blockIdx.x * 256 + threadIdx.x;     // 65536
    int k = idx >> 8;
    int c = idx & 255;
    const float* w = (c < 128) ? wz : wh;
    int cc = c & 127;
    // w shape (2,1,384,128): w[a,0,k,j] = w[a*384*128 + k*128 + j]
    float v = w[k * 128 + cc] + w[384 * 128 + k * 128 + cc];
    W1T[c * 256 + k] = (f16)v;
}

// W2T[c][k], c in [0,128): c<64 -> Az2 col c ; else Ah2 col c-64. k in [0,128).
__global__ void prep_w2(const float* __restrict__ wz, const float* __restrict__ wh,
                        f16* __restrict__ W2T) {
    int idx = blockIdx.x * 256 + threadIdx.x;     // 16384
    int k = idx >> 7;
    int c = idx & 127;
    const float* w = (c < 64) ? wz : wh;
    int cc = c & 63;
    // w shape (2,1,192,64)
    float v = w[k * 64 + cc] + w[192 * 64 + k * 64 + cc];
    W2T[c * 128 + k] = (f16)v;
}

// ---------- layer 1: h1 = relu((1-sigmoid(x@Az+bz)) * tanh(x@Ah+bh)) ----------
// grid (782, 2): 128 rows x 64 gate-cols per block (128 combined cols). 256 thr = 4 waves.
__global__ __launch_bounds__(256) void k1_layer1(const float* __restrict__ x,
                                                 const f16* __restrict__ W1T,
                                                 const float* __restrict__ bz,
                                                 const float* __restrict__ bh,
                                                 f16* __restrict__ h1) {
    __shared__ f16 Xs[128 * LDS_STRIDE];
    __shared__ f16 Ws[128 * LDS_STRIDE];

    const int tid  = threadIdx.x;
    const int r0   = blockIdx.x * 128;
    const int jt   = blockIdx.y;                  // 0/1 -> gate cols 64*jt..
    const int wave = tid >> 6, lane = tid & 63;
    const int ln   = lane & 15, quad = lane >> 4;
    const int rh   = wave >> 1, jh = wave & 1;    // wave: rows 64*rh.., j 32*jh..

    f32x4 acc[4][2][2];                           // [rb][jb][gate]
#pragma unroll
    for (int a = 0; a < 4; ++a)
#pragma unroll
        for (int b = 0; b < 2; ++b)
#pragma unroll
            for (int g = 0; g < 2; ++g) acc[a][b][g] = (f32x4){0.f, 0.f, 0.f, 0.f};

    for (int kb = 0; kb < 256; kb += 32) {
        // stage X tile: 128 rows x 32 k (fp32 -> f16)
#pragma unroll
        for (int it = 0; it < 4; ++it) {
            const int flat = (it << 8) + tid;     // 0..1023
            const int row = flat >> 3, c4 = flat & 7;
            const int gr = r0 + row;
            float4 v = {0.f, 0.f, 0.f, 0.f};
            if (gr < N_ROWS) v = *(const float4*)(x + (size_t)gr * 256 + kb + (c4 << 2));
            f16x4 p = {(f16)v.x, (f16)v.y, (f16)v.z, (f16)v.w};
            *(f16x4*)&Xs[row * LDS_STRIDE + (c4 << 2)] = p;
        }
        // stage W tile: 128 combined cols (64 z then 64 h) x 32 k (already f16)
#pragma unroll
        for (int it = 0; it < 2; ++it) {
            const int flat = (it << 8) + tid;     // 0..511
            const int row = flat >> 2, q = flat & 3;
            const int grow = 64 * jt + row + ((row < 64) ? 0 : 64);
            f16x8 wv = *(const f16x8*)(W1T + (size_t)grow * 256 + kb + (q << 3));
            *(f16x8*)&Ws[row * LDS_STRIDE + (q << 3)] = wv;
        }
        __syncthreads();

        f16x8 af[4], bf[2][2];
#pragma unroll
        for (int rb = 0; rb < 4; ++rb)
            af[rb] = *(const f16x8*)&Xs[(64 * rh + 16 * rb + ln) * LDS_STRIDE + quad * 8];
#pragma unroll
        for (int jb = 0; jb < 2; ++jb) {
            bf[jb][0] = *(const f16x8*)&Ws[(32 * jh + 16 * jb + ln) * LDS_STRIDE + quad * 8];
            bf[jb][1] = *(const f16x8*)&Ws[(64 + 32 * jh + 16 * jb + ln) * LDS_STRIDE + quad * 8];
        }
#pragma unroll
        for (int rb = 0; rb < 4; ++rb)
#pragma unroll
            for (int jb = 0; jb < 2; ++jb)
#pragma unroll
                for (int g = 0; g < 2; ++g)
                    acc[rb][jb][g] = __builtin_amdgcn_mfma_f32_16x16x32_f16(
                        af[rb], bf[jb][g], acc[rb][jb][g], 0, 0, 0);
        __syncthreads();
    }

    // epilogue: fused gates, store f16 h1
#pragma unroll
    for (int jb = 0; jb < 2; ++jb) {
        const int jl = 32 * jh + 16 * jb + ln;    // 0..63 local
        const int jg = 64 * jt + jl;              // 0..127 global
        const float bzv = bz[jg];
        const float bhv = bh[jg];
#pragma unroll
        for (int rb = 0; rb < 4; ++rb) {
#pragma unroll
            for (int i = 0; i < 4; ++i) {
                const int row = r0 + 64 * rh + 16 * rb + 4 * quad + i;
                float zp = acc[rb][jb][0][i] + bzv;
                float hp = acc[rb][jb][1][i] + bhv;
                float ex = __expf(2.0f * hp);
                float th = 1.0f - 2.0f / (ex + 1.0f);      // tanh(hp)
                float sg = 1.0f / (1.0f + __expf(zp));     // 1 - sigmoid(zp)
                float g = fmaxf(th * sg, 0.0f);
                h1[(size_t)row * 128 + jg] = (f16)g;
            }
        }
    }
}

// ---------- layer 2: h2 = relu((1-sigmoid(h1@Az2+bz2)) * tanh(h1@Ah2+bh2)) ----------
// grid (782): 128 rows x all 64 gate-cols (128 combined cols). 256 thr = 4 waves.
__global__ __launch_bounds__(256) void k2_layer2(const f16* __restrict__ h1,
                                                 const f16* __restrict__ W2T,
                                                 const float* __restrict__ bz,
                                                 const float* __restrict__ bh,
                                                 f16* __restrict__ h2) {
    __shared__ f16 Xs[128 * LDS_STRIDE];
    __shared__ f16 Ws[128 * LDS_STRIDE];

    const int tid  = threadIdx.x;
    const int r0   = blockIdx.x * 128;
    const int wave = tid >> 6, lane = tid & 63;
    const int ln   = lane & 15, quad = lane >> 4;
    const int rh   = wave >> 1, jh = wave & 1;

    f32x4 acc[4][2][2];
#pragma unroll
    for (int a = 0; a < 4; ++a)
#pragma unroll
        for (int b = 0; b < 2; ++b)
#pragma unroll
            for (int g = 0; g < 2; ++g) acc[a][b][g] = (f32x4){0.f, 0.f, 0.f, 0.f};

    for (int kb = 0; kb < 128; kb += 32) {
#pragma unroll
        for (int it = 0; it < 2; ++it) {
            const int flat = (it << 8) + tid;
            const int row = flat >> 2, q = flat & 3;
            f16x8 xv = *(const f16x8*)(h1 + (size_t)(r0 + row) * 128 + kb + (q << 3));
            *(f16x8*)&Xs[row * LDS_STRIDE + (q << 3)] = xv;
            f16x8 wv = *(const f16x8*)(W2T + (size_t)row * 128 + kb + (q << 3));
            *(f16x8*)&Ws[row * LDS_STRIDE + (q << 3)] = wv;
        }
        __syncthreads();

        f16x8 af[4], bf[2][2];
#pragma unroll
        for (int rb = 0; rb < 4; ++rb)
            af[rb] = *(const f16x8*)&Xs[(64 * rh + 16 * rb + ln) * LDS_STRIDE + quad * 8];
#pragma unroll
        for (int jb = 0; jb < 2; ++jb) {
            bf[jb][0] = *(const f16x8*)&Ws[(32 * jh + 16 * jb + ln) * LDS_STRIDE + quad * 8];
            bf[jb][1] = *(const f16x8*)&Ws[(64 + 32 * jh + 16 * jb + ln) * LDS_STRIDE + quad * 8];
        }
#pragma unroll
        for (int rb = 0; rb < 4; ++rb)
#pragma unroll
            for (int jb = 0; jb < 2; ++jb)
#pragma unroll
                for (int g = 0; g < 2; ++g)
                    acc[rb][jb][g] = __builtin_amdgcn_mfma_f32_16x16x32_f16(
                        af[rb], bf[jb][g], acc[rb][jb][g], 0, 0, 0);
        __syncthreads();
    }

#pragma unroll
    for (int jb = 0; jb < 2; ++jb) {
        const int j = 32 * jh + 16 * jb + ln;     // 0..63
        const float bzv = bz[j];
        const float bhv = bh[j];
#pragma unroll
        for (int rb = 0; rb < 4; ++rb) {
#pragma unroll
            for (int i = 0; i < 4; ++i) {
                const int row = r0 + 64 * rh + 16 * rb + 4 * quad + i;
                float zp = acc[rb][jb][0][i] + bzv;
                float hp = acc[rb][jb][1][i] + bhv;
                float ex = __expf(2.0f * hp);
                float th = 1.0f - 2.0f / (ex + 1.0f);
                float sg = 1.0f / (1.0f + __expf(zp));
                float g = fmaxf(th * sg, 0.0f);
                h2[(size_t)row * 64 + j] = (f16)g;
            }
        }
    }
}

// ---------- lin layers: out = relu(h2@W1+b1) @ W2 + b2 ----------
__global__ __launch_bounds__(256) void k3_lin(const f16* __restrict__ h2,
                                              const float* __restrict__ wl1,
                                              const float* __restrict__ bl1,
                                              const float* __restrict__ wl2,
                                              const float* __restrict__ bl2,
                                              float* __restrict__ out) {
    const int row = blockIdx.x * 256 + threadIdx.x;
    if (row >= N_ROWS) return;
    const f16x8* hp = (const f16x8*)(h2 + (size_t)row * 64);
    float xf[64];
#pragma unroll
    for (int i = 0; i < 8; ++i) {
        f16x8 v = hp[i];
#pragma unroll
        for (int j = 0; j < 8; ++j) xf[i * 8 + j] = (float)v[j];
    }
    float acc[16];
#pragma unroll
    for (int j = 0; j < 16; ++j) acc[j] = bl1[j];
#pragma unroll
    for (int k = 0; k < 64; ++k) {
#pragma unroll
        for (int j = 0; j < 16; ++j) acc[j] = fmaf(xf[k], wl1[k * 16 + j], acc[j]);
    }
    float o = bl2[0];
#pragma unroll
    for (int j = 0; j < 16; ++j) o = fmaf(fmaxf(acc[j], 0.0f), wl2[j], o);
    out[row] = o;
}

// ---------- launch ----------
extern "C" void kernel_launch(void* const* d_in, const int* in_sizes, int n_in,
                              void* d_out, int out_size, void* d_ws, size_t ws_size,
                              hipStream_t stream) {
    const float* x   = (const float*)d_in[0];
    const float* wz1 = (const float*)d_in[3];
    const float* bz1 = (const float*)d_in[4];
    const float* wh1 = (const float*)d_in[7];
    const float* bh1 = (const float*)d_in[8];
    const float* wz2 = (const float*)d_in[9];
    const float* bz2 = (const float*)d_in[10];
    const float* wh2 = (const float*)d_in[13];
    const float* bh2 = (const float*)d_in[14];
    const float* wl1 = (const float*)d_in[15];
    const float* bl1 = (const float*)d_in[16];
    const float* wl2 = (const float*)d_in[17];
    const float* bl2 = (const float*)d_in[18];

    char* ws = (char*)d_ws;
    f16* W1T = (f16*)(ws + W1T_OFF);
    f16* W2T = (f16*)(ws + W2T_OFF);
    f16* h1  = (f16*)(ws + H1_OFF);
    f16* h2  = (f16*)(ws + H2_OFF);
    float* out = (float*)d_out;

    prep_w1<<<256, 256, 0, stream>>>(wz1, wh1, W1T);
    prep_w2<<<64, 256, 0, stream>>>(wz2, wh2, W2T);
    k1_layer1<<<dim3(RT, 2), 256, 0, stream>>>(x, W1T, bz1, bh1, h1);
    k2_layer2<<<RT, 256, 0, stream>>>(h1, W2T, bz2, bh2, h2);
    k3_lin<<<391, 256, 0, stream>>>(h2, wl1, bl1, wl2, bl2, out);
}

// Round 2
// 256.270 us; speedup vs baseline: 1.0913x; 1.0913x over previous
//
#include <hip/hip_runtime.h>

// ---------- types ----------
typedef _Float16 f16;
typedef _Float16 f16x8 __attribute__((ext_vector_type(8)));
typedef float    f32x4 __attribute__((ext_vector_type(4)));

#define N_ROWS 100000
#define RT 782            // row tiles of 128 -> 100096 padded rows
#define PAD_ROWS (RT * 128)
#define LS 72             // LDS row stride in f16: 36 dwords -> conflict-free b128 r/w

// ws layout (bytes)
#define W1T_OFF 0
#define W1T_BYTES (256 * 256 * 2)
#define W2T_OFF (W1T_OFF + W1T_BYTES)
#define W2T_BYTES (128 * 128 * 2)
#define H1_OFF (W2T_OFF + W2T_BYTES)
#define H1_BYTES (PAD_ROWS * 128 * 2)
#define H2_OFF (H1_OFF + H1_BYTES)

// ---------- prep: combined, transposed f16 weights ----------
__global__ void prep_w1(const float* __restrict__ wz, const float* __restrict__ wh,
                        f16* __restrict__ W1T) {
    int idx = blockIdx.x * 256 + threadIdx.x;     // 65536
    int k = idx >> 8;
    int c = idx & 255;
    const float* w = (c < 128) ? wz : wh;
    int cc = c & 127;
    float v = w[k * 128 + cc] + w[384 * 128 + k * 128 + cc];
    W1T[c * 256 + k] = (f16)v;
}

__global__ void prep_w2(const float* __restrict__ wz, const float* __restrict__ wh,
                        f16* __restrict__ W2T) {
    int idx = blockIdx.x * 256 + threadIdx.x;     // 16384
    int k = idx >> 7;
    int c = idx & 127;
    const float* w = (c < 64) ? wz : wh;
    int cc = c & 63;
    float v = w[k * 64 + cc] + w[192 * 64 + k * 64 + cc];
    W2T[c * 128 + k] = (f16)v;
}

// ---------- layer 1 ----------
// grid (782, 2): 128 rows x 64 gate-cols (=128 combined cols) per block.
// 4 waves, each 64 rows x 32 gate-cols (both z & h accs in-lane).
// K-loop: 4 iters of K=64, batched register staging + next-iter prefetch.
__global__ __launch_bounds__(256) void k1_layer1(const float* __restrict__ x,
                                                 const f16* __restrict__ W1T,
                                                 const float* __restrict__ bz,
                                                 const float* __restrict__ bh,
                                                 f16* __restrict__ h1) {
    __shared__ __align__(16) f16 Xs[128 * LS];
    __shared__ __align__(16) f16 Ws[128 * LS];

    const int tid  = threadIdx.x;
    const int r0   = blockIdx.x * 128;
    const int jt   = blockIdx.y;
    const int lane = tid & 63, wave = tid >> 6;
    const int ln   = lane & 15, quad = lane >> 4;
    const int rh   = wave >> 1, jh = wave & 1;

    float4 xa[4], xb[4];
    f16x8  wv[4];

#define K1_LOAD(KB)                                                              \
    _Pragma("unroll")                                                            \
    for (int it2 = 0; it2 < 4; ++it2) {                                          \
        const int idx = (it2 << 8) + tid;                                        \
        const int row = idx >> 3, cc = idx & 7;                                  \
        const int gr  = (r0 + row < N_ROWS) ? (r0 + row) : (N_ROWS - 1);         \
        const float* xp = x + (size_t)gr * 256 + (KB) + (cc << 3);               \
        xa[it2] = *(const float4*)xp;                                            \
        xb[it2] = *(const float4*)(xp + 4);                                      \
        const int grow = (jt << 6) + row + ((row < 64) ? 0 : 64);                \
        wv[it2] = *(const f16x8*)(W1T + ((size_t)grow << 8) + (KB) + (cc << 3)); \
    }

    K1_LOAD(0)

    f32x4 acc[4][2][2];
#pragma unroll
    for (int a = 0; a < 4; ++a)
#pragma unroll
        for (int b = 0; b < 2; ++b)
#pragma unroll
            for (int g = 0; g < 2; ++g) acc[a][b][g] = (f32x4){0.f, 0.f, 0.f, 0.f};

    for (int kb = 0; kb < 256; kb += 64) {
        // commit staged registers to LDS (f32 -> f16 for X)
#pragma unroll
        for (int it2 = 0; it2 < 4; ++it2) {
            const int idx = (it2 << 8) + tid;
            const int row = idx >> 3, cc = idx & 7;
            f16x8 p = {(f16)xa[it2].x, (f16)xa[it2].y, (f16)xa[it2].z, (f16)xa[it2].w,
                       (f16)xb[it2].x, (f16)xb[it2].y, (f16)xb[it2].z, (f16)xb[it2].w};
            *(f16x8*)&Xs[row * LS + (cc << 3)] = p;
            *(f16x8*)&Ws[row * LS + (cc << 3)] = wv[it2];
        }
        __syncthreads();
        if (kb < 192) { K1_LOAD(kb + 64) }   // prefetch flies during MFMA below

#pragma unroll
        for (int kc = 0; kc < 2; ++kc) {
            f16x8 af[4], bzf[2], bhf[2];
#pragma unroll
            for (int rb = 0; rb < 4; ++rb)
                af[rb] = *(const f16x8*)&Xs[(64 * rh + 16 * rb + ln) * LS + kc * 32 + quad * 8];
#pragma unroll
            for (int cb = 0; cb < 2; ++cb) {
                bzf[cb] = *(const f16x8*)&Ws[(32 * jh + 16 * cb + ln) * LS + kc * 32 + quad * 8];
                bhf[cb] = *(const f16x8*)&Ws[(64 + 32 * jh + 16 * cb + ln) * LS + kc * 32 + quad * 8];
            }
#pragma unroll
            for (int rb = 0; rb < 4; ++rb)
#pragma unroll
                for (int cb = 0; cb < 2; ++cb) {
                    acc[rb][cb][0] = __builtin_amdgcn_mfma_f32_16x16x32_f16(af[rb], bzf[cb], acc[rb][cb][0], 0, 0, 0);
                    acc[rb][cb][1] = __builtin_amdgcn_mfma_f32_16x16x32_f16(af[rb], bhf[cb], acc[rb][cb][1], 0, 0, 0);
                }
        }
        __syncthreads();
    }
#undef K1_LOAD

    // epilogue: fused gates, store f16 h1 (pad rows stored too -- ws-backed)
#pragma unroll
    for (int cb = 0; cb < 2; ++cb) {
        const int jg = (jt << 6) + 32 * jh + 16 * cb + ln;
        const float bzv = bz[jg];
        const float bhv = bh[jg];
#pragma unroll
        for (int rb = 0; rb < 4; ++rb) {
            const int rbase = r0 + 64 * rh + 16 * rb + 4 * quad;
#pragma unroll
            for (int i = 0; i < 4; ++i) {
                float zp = acc[rb][cb][0][i] + bzv;
                float hp = acc[rb][cb][1][i] + bhv;
                float ex = __expf(2.0f * hp);
                float th = 1.0f - 2.0f / (ex + 1.0f);      // tanh(hp)
                float sg = 1.0f / (1.0f + __expf(zp));     // 1 - sigmoid(zp)
                float g = fmaxf(th * sg, 0.0f);
                h1[(size_t)(rbase + i) * 128 + jg] = (f16)g;
            }
        }
    }
}

// ---------- layer 2 ----------
// grid 782: 128 rows x 64 gate-cols (=128 combined). Same structure, K=128, 2 iters.
__global__ __launch_bounds__(256) void k2_layer2(const f16* __restrict__ h1,
                                                 const f16* __restrict__ W2T,
                                                 const float* __restrict__ bz,
                                                 const float* __restrict__ bh,
                                                 f16* __restrict__ h2) {
    __shared__ __align__(16) f16 Xs[128 * LS];
    __shared__ __align__(16) f16 Ws[128 * LS];

    const int tid  = threadIdx.x;
    const int r0   = blockIdx.x * 128;
    const int lane = tid & 63, wave = tid >> 6;
    const int ln   = lane & 15, quad = lane >> 4;
    const int rh   = wave >> 1, jh = wave & 1;

    f16x8 xv[4], wv[4];

#define K2_LOAD(KB)                                                               \
    _Pragma("unroll")                                                             \
    for (int it2 = 0; it2 < 4; ++it2) {                                           \
        const int idx = (it2 << 8) + tid;                                         \
        const int row = idx >> 3, cc = idx & 7;                                   \
        xv[it2] = *(const f16x8*)(h1 + ((size_t)(r0 + row) << 7) + (KB) + (cc << 3)); \
        wv[it2] = *(const f16x8*)(W2T + ((size_t)row << 7) + (KB) + (cc << 3));   \
    }

    K2_LOAD(0)

    f32x4 acc[4][2][2];
#pragma unroll
    for (int a = 0; a < 4; ++a)
#pragma unroll
        for (int b = 0; b < 2; ++b)
#pragma unroll
            for (int g = 0; g < 2; ++g) acc[a][b][g] = (f32x4){0.f, 0.f, 0.f, 0.f};

    for (int kb = 0; kb < 128; kb += 64) {
#pragma unroll
        for (int it2 = 0; it2 < 4; ++it2) {
            const int idx = (it2 << 8) + tid;
            const int row = idx >> 3, cc = idx & 7;
            *(f16x8*)&Xs[row * LS + (cc << 3)] = xv[it2];
            *(f16x8*)&Ws[row * LS + (cc << 3)] = wv[it2];
        }
        __syncthreads();
        if (kb == 0) { K2_LOAD(64) }

#pragma unroll
        for (int kc = 0; kc < 2; ++kc) {
            f16x8 af[4], bzf[2], bhf[2];
#pragma unroll
            for (int rb = 0; rb < 4; ++rb)
                af[rb] = *(const f16x8*)&Xs[(64 * rh + 16 * rb + ln) * LS + kc * 32 + quad * 8];
#pragma unroll
            for (int cb = 0; cb < 2; ++cb) {
                bzf[cb] = *(const f16x8*)&Ws[(32 * jh + 16 * cb + ln) * LS + kc * 32 + quad * 8];
                bhf[cb] = *(const f16x8*)&Ws[(64 + 32 * jh + 16 * cb + ln) * LS + kc * 32 + quad * 8];
            }
#pragma unroll
            for (int rb = 0; rb < 4; ++rb)
#pragma unroll
                for (int cb = 0; cb < 2; ++cb) {
                    acc[rb][cb][0] = __builtin_amdgcn_mfma_f32_16x16x32_f16(af[rb], bzf[cb], acc[rb][cb][0], 0, 0, 0);
                    acc[rb][cb][1] = __builtin_amdgcn_mfma_f32_16x16x32_f16(af[rb], bhf[cb], acc[rb][cb][1], 0, 0, 0);
                }
        }
        __syncthreads();
    }
#undef K2_LOAD

#pragma unroll
    for (int cb = 0; cb < 2; ++cb) {
        const int j = 32 * jh + 16 * cb + ln;
        const float bzv = bz[j];
        const float bhv = bh[j];
#pragma unroll
        for (int rb = 0; rb < 4; ++rb) {
            const int rbase = r0 + 64 * rh + 16 * rb + 4 * quad;
#pragma unroll
            for (int i = 0; i < 4; ++i) {
                float zp = acc[rb][cb][0][i] + bzv;
                float hp = acc[rb][cb][1][i] + bhv;
                float ex = __expf(2.0f * hp);
                float th = 1.0f - 2.0f / (ex + 1.0f);
                float sg = 1.0f / (1.0f + __expf(zp));
                float g = fmaxf(th * sg, 0.0f);
                h2[(size_t)(rbase + i) * 64 + j] = (f16)g;
            }
        }
    }
}

// ---------- lin layers: out = relu(h2@W1+b1) @ W2 + b2 ----------
__global__ __launch_bounds__(256) void k3_lin(const f16* __restrict__ h2,
                                              const float* __restrict__ wl1,
                                              const float* __restrict__ bl1,
                                              const float* __restrict__ wl2,
                                              const float* __restrict__ bl2,
                                              float* __restrict__ out) {
    const int row = blockIdx.x * 256 + threadIdx.x;
    if (row >= N_ROWS) return;
    const f16x8* hp = (const f16x8*)(h2 + (size_t)row * 64);
    float xf[64];
#pragma unroll
    for (int i = 0; i < 8; ++i) {
        f16x8 v = hp[i];
#pragma unroll
        for (int j = 0; j < 8; ++j) xf[i * 8 + j] = (float)v[j];
    }
    float acc[16];
#pragma unroll
    for (int j = 0; j < 16; ++j) acc[j] = bl1[j];
#pragma unroll
    for (int k = 0; k < 64; ++k) {
#pragma unroll
        for (int j = 0; j < 16; ++j) acc[j] = fmaf(xf[k], wl1[k * 16 + j], acc[j]);
    }
    float o = bl2[0];
#pragma unroll
    for (int j = 0; j < 16; ++j) o = fmaf(fmaxf(acc[j], 0.0f), wl2[j], o);
    out[row] = o;
}

// ---------- launch ----------
extern "C" void kernel_launch(void* const* d_in, const int* in_sizes, int n_in,
                              void* d_out, int out_size, void* d_ws, size_t ws_size,
                              hipStream_t stream) {
    const float* x   = (const float*)d_in[0];
    const float* wz1 = (const float*)d_in[3];
    const float* bz1 = (const float*)d_in[4];
    const float* wh1 = (const float*)d_in[7];
    const float* bh1 = (const float*)d_in[8];
    const float* wz2 = (const float*)d_in[9];
    const float* bz2 = (const float*)d_in[10];
    const float* wh2 = (const float*)d_in[13];
    const float* bh2 = (const float*)d_in[14];
    const float* wl1 = (const float*)d_in[15];
    const float* bl1 = (const float*)d_in[16];
    const float* wl2 = (const float*)d_in[17];
    const float* bl2 = (const float*)d_in[18];

    char* ws = (char*)d_ws;
    f16* W1T = (f16*)(ws + W1T_OFF);
    f16* W2T = (f16*)(ws + W2T_OFF);
    f16* h1  = (f16*)(ws + H1_OFF);
    f16* h2  = (f16*)(ws + H2_OFF);
    float* out = (float*)d_out;

    prep_w1<<<256, 256, 0, stream>>>(wz1, wh1, W1T);
    prep_w2<<<64, 256, 0, stream>>>(wz2, wh2, W2T);
    k1_layer1<<<dim3(RT, 2), 256, 0, stream>>>(x, W1T, bz1, bh1, h1);
    k2_layer2<<<RT, 256, 0, stream>>>(h1, W2T, bz2, bh2, h2);
    k3_lin<<<391, 256, 0, stream>>>(h2, wl1, bl1, wl2, bl2, out);
}

// Round 3
// 246.660 us; speedup vs baseline: 1.1338x; 1.0390x over previous
//
#include <hip/hip_runtime.h>

// ---------- types ----------
typedef _Float16 f16;
typedef _Float16 f16x4 __attribute__((ext_vector_type(4)));
typedef _Float16 f16x8 __attribute__((ext_vector_type(8)));
typedef float    f32x4 __attribute__((ext_vector_type(4)));

#define N_ROWS 100000
#define RT 782            // 782 * 128 = 100096 padded rows

// ws layout (bytes): only weights now
#define W1T_OFF 0
#define W1T_BYTES (256 * 256 * 2)
#define W2T_OFF W1T_BYTES

// LDS arena (bytes)
#define A_XS 0            // 128*72*2  = 18432   (X tile, padded, f16)
#define A_WS 18432        // 32768              (W1 K-chunk, swizzled)  -> 51200
#define A_H1 0            // 128*136*2 = 34816   (h1 tile, after P1)
#define A_W2 36864        // 32768              (whole W2, swizzled)    -> 69632
#define A_H2 0            // 128*72*2  = 18432   (h2 tile, after P2)
#define ARENA_BYTES 69632
#define LSX 72
#define LSH1 136
#define LSH2 72

__device__ __forceinline__ void glds16(const void* g, void* l) {
    __builtin_amdgcn_global_load_lds((const __attribute__((address_space(1))) void*)g,
                                     (__attribute__((address_space(3))) void*)l, 16, 0, 0);
}

// ---------- prep: combined, transposed f16 weights ----------
__global__ void prep_w1(const float* __restrict__ wz, const float* __restrict__ wh,
                        f16* __restrict__ W1T) {
    int idx = blockIdx.x * 256 + threadIdx.x;     // 65536
    int k = idx >> 8;
    int c = idx & 255;
    const float* w = (c < 128) ? wz : wh;
    int cc = c & 127;
    float v = w[k * 128 + cc] + w[384 * 128 + k * 128 + cc];
    W1T[c * 256 + k] = (f16)v;
}

__global__ void prep_w2(const float* __restrict__ wz, const float* __restrict__ wh,
                        f16* __restrict__ W2T) {
    int idx = blockIdx.x * 256 + threadIdx.x;     // 16384
    int k = idx >> 7;
    int c = idx & 127;
    const float* w = (c < 64) ? wz : wh;
    int cc = c & 63;
    float v = w[k * 64 + cc] + w[192 * 64 + k * 64 + cc];
    W2T[c * 128 + k] = (f16)v;
}

// ---------- fused: 128 rows/block through L1 -> L2 -> lin ----------
__global__ __launch_bounds__(256, 2) void fused(
    const float* __restrict__ x,
    const f16* __restrict__ W1T, const f16* __restrict__ W2T,
    const float* __restrict__ bz1, const float* __restrict__ bh1,
    const float* __restrict__ bz2, const float* __restrict__ bh2,
    const float* __restrict__ wl1, const float* __restrict__ bl1,
    const float* __restrict__ wl2, const float* __restrict__ bl2,
    float* __restrict__ out)
{
    __shared__ __align__(16) char arena[ARENA_BYTES];
    const int tid = threadIdx.x, lane = tid & 63, wave = tid >> 6;
    const int ln = lane & 15, quad = lane >> 4;
    const int rh = wave >> 1, jh = wave & 1;
    const int r0 = blockIdx.x * 128;

    f16* Xs = (f16*)(arena + A_XS);
    f16* Ws = (f16*)(arena + A_WS);

    // ================= Phase 1: h1 = gates(X @ W1), 128x128 =================
    // Swapped operands: A = W1 (m = 256 comb cols), B = X (n = 128 rows).
    // Wave (rh,jh): n rows 64*rh..+64 (nt 0..3), m comb cols: jh half (mt 0..7).
    float4 xa[4], xb[4];

#define X_LOAD(KB)                                                               \
    _Pragma("unroll")                                                            \
    for (int it2 = 0; it2 < 4; ++it2) {                                          \
        const int idx = (it2 << 8) + tid;                                        \
        const int row = idx >> 3, cc = idx & 7;                                  \
        const int gr = (r0 + row < N_ROWS) ? (r0 + row) : (N_ROWS - 1);          \
        const float* xp = x + (size_t)gr * 256 + (KB) + (cc << 3);               \
        xa[it2] = *(const float4*)xp;                                            \
        xb[it2] = *(const float4*)(xp + 4);                                      \
    }

    X_LOAD(0)

    f32x4 acc[8][4];
#pragma unroll
    for (int a = 0; a < 8; ++a)
#pragma unroll
        for (int b = 0; b < 4; ++b) acc[a][b] = (f32x4){0.f, 0.f, 0.f, 0.f};

    const int wrloc = lane >> 3, wslot = lane & 7;   // W1 glds lane mapping

    for (int kb = 0; kb < 256; kb += 64) {
        // commit X tile (fp32 -> f16, padded stride)
#pragma unroll
        for (int it2 = 0; it2 < 4; ++it2) {
            const int idx = (it2 << 8) + tid;
            const int row = idx >> 3, cc = idx & 7;
            f16x8 p = {(f16)xa[it2].x, (f16)xa[it2].y, (f16)xa[it2].z, (f16)xa[it2].w,
                       (f16)xb[it2].x, (f16)xb[it2].y, (f16)xb[it2].z, (f16)xb[it2].w};
            *(f16x8*)&Xs[row * LSX + (cc << 3)] = p;
        }
        // W1 K-chunk via global_load_lds, XOR-swizzled fetch (slot s holds k-slot s^(col&7))
#pragma unroll
        for (int c = 0; c < 8; ++c) {
            const int h = wave * 8 + c;              // chunk: 8 cols x 8 slots = 1KB
            const int col = h * 8 + wrloc;
            glds16(W1T + (size_t)col * 256 + kb + ((wslot ^ (col & 7)) << 3),
                   Ws + h * 512);
        }
        __syncthreads();
        if (kb < 192) { X_LOAD(kb + 64) }            // prefetch during MFMA

#pragma unroll
        for (int kc = 0; kc < 2; ++kc) {
            f16x8 bf[4];
#pragma unroll
            for (int nt = 0; nt < 4; ++nt)
                bf[nt] = *(const f16x8*)&Xs[((rh << 6) + (nt << 4) + ln) * LSX + kc * 32 + quad * 8];
            const int sw = ((kc * 4 + quad) ^ (ln & 7)) << 3;
#pragma unroll
            for (int mt = 0; mt < 8; ++mt) {
                const int col = ((mt & 3) << 4) + (jh << 6) + ((mt >> 2) << 7) + ln;
                f16x8 af = *(const f16x8*)&Ws[col * 64 + sw];
#pragma unroll
                for (int nt = 0; nt < 4; ++nt)
                    acc[mt][nt] = __builtin_amdgcn_mfma_f32_16x16x32_f16(af, bf[nt], acc[mt][nt], 0, 0, 0);
            }
        }
        __syncthreads();
    }
#undef X_LOAD

    // P1 epilogue: gates -> h1s (row-major, padded). D: col(lane&15)=X row, row(quad*4+i)=comb col.
    f16* h1s = (f16*)(arena + A_H1);
#pragma unroll
    for (int mtp = 0; mtp < 4; ++mtp) {
        const int jg0 = (jh << 6) + (mtp << 4) + (quad << 2);   // gate col base, 4 consecutive
        const float4 zb4 = *(const float4*)(bz1 + jg0);
        const float4 hb4 = *(const float4*)(bh1 + jg0);
        const float zbv[4] = {zb4.x, zb4.y, zb4.z, zb4.w};
        const float hbv[4] = {hb4.x, hb4.y, hb4.z, hb4.w};
#pragma unroll
        for (int nt = 0; nt < 4; ++nt) {
            const int row = (rh << 6) + (nt << 4) + ln;
            f16x4 pk;
#pragma unroll
            for (int i = 0; i < 4; ++i) {
                float zp = acc[mtp][nt][i] + zbv[i];
                float hp = acc[mtp + 4][nt][i] + hbv[i];
                float ex = __expf(2.0f * hp);
                float th = 1.0f - 2.0f / (ex + 1.0f);      // tanh(hp)
                float sg = 1.0f / (1.0f + __expf(zp));     // 1 - sigmoid(zp)
                pk[i] = (f16)fmaxf(th * sg, 0.0f);
            }
            *(f16x4*)&h1s[row * LSH1 + jg0] = pk;
        }
    }

    // stage whole W2 (128x128 f16 = 32KB), swizzled: 4 cols x 16 slots per chunk
    f16* W2s = (f16*)(arena + A_W2);
    {
        const int rloc = lane >> 4, s = lane & 15;
#pragma unroll
        for (int c = 0; c < 8; ++c) {
            const int h = wave * 8 + c;
            const int col = h * 4 + rloc;
            glds16(W2T + (size_t)col * 128 + ((s ^ (col & 15)) << 3), W2s + h * 512);
        }
    }
    __syncthreads();

    // ================= Phase 2: h2 = gates(h1 @ W2), 128x64 =================
    f32x4 acc2[4][4];
#pragma unroll
    for (int a = 0; a < 4; ++a)
#pragma unroll
        for (int b = 0; b < 4; ++b) acc2[a][b] = (f32x4){0.f, 0.f, 0.f, 0.f};

#pragma unroll
    for (int kc = 0; kc < 4; ++kc) {
        f16x8 bf[4];
#pragma unroll
        for (int nt = 0; nt < 4; ++nt)
            bf[nt] = *(const f16x8*)&h1s[((rh << 6) + (nt << 4) + ln) * LSH1 + kc * 32 + quad * 8];
        const int sw = ((kc * 4 + quad) ^ ln) << 3;
#pragma unroll
        for (int mt = 0; mt < 4; ++mt) {
            const int col = ((mt & 1) << 4) + (jh << 5) + ((mt >> 1) << 6) + ln;
            f16x8 af = *(const f16x8*)&W2s[col * 128 + sw];
#pragma unroll
            for (int nt = 0; nt < 4; ++nt)
                acc2[mt][nt] = __builtin_amdgcn_mfma_f32_16x16x32_f16(af, bf[nt], acc2[mt][nt], 0, 0, 0);
        }
    }
    __syncthreads();   // all h1s/W2s reads done before h2s overwrites arena

    f16* h2s = (f16*)(arena + A_H2);
#pragma unroll
    for (int mtp = 0; mtp < 2; ++mtp) {
        const int jg0 = (jh << 5) + (mtp << 4) + (quad << 2);
        const float4 zb4 = *(const float4*)(bz2 + jg0);
        const float4 hb4 = *(const float4*)(bh2 + jg0);
        const float zbv[4] = {zb4.x, zb4.y, zb4.z, zb4.w};
        const float hbv[4] = {hb4.x, hb4.y, hb4.z, hb4.w};
#pragma unroll
        for (int nt = 0; nt < 4; ++nt) {
            const int row = (rh << 6) + (nt << 4) + ln;
            f16x4 pk;
#pragma unroll
            for (int i = 0; i < 4; ++i) {
                float zp = acc2[mtp][nt][i] + zbv[i];
                float hp = acc2[mtp + 2][nt][i] + hbv[i];
                float ex = __expf(2.0f * hp);
                float th = 1.0f - 2.0f / (ex + 1.0f);
                float sg = 1.0f / (1.0f + __expf(zp));
                pk[i] = (f16)fmaxf(th * sg, 0.0f);
            }
            *(f16x4*)&h2s[row * LSH2 + jg0] = pk;
        }
    }
    __syncthreads();

    // ================= Phase 3: out = relu(h2 @ wl1 + bl1) @ wl2 + bl2 =================
    // Non-swapped: A = h2 (wave w: rows 32w..+32, 2 m-tiles), B = wl1 (16 cols).
    const float blv  = bl1[ln];
    const float wlv  = wl2[ln];
    const float bl2v = bl2[0];
    f16x8 bfr[2];
#pragma unroll
    for (int kc = 0; kc < 2; ++kc)
#pragma unroll
        for (int j = 0; j < 8; ++j)
            bfr[kc][j] = (f16)wl1[(kc * 32 + quad * 8 + j) * 16 + ln];

    f32x4 acc3[2] = {(f32x4){0.f, 0.f, 0.f, 0.f}, (f32x4){0.f, 0.f, 0.f, 0.f}};
#pragma unroll
    for (int t2 = 0; t2 < 2; ++t2)
#pragma unroll
        for (int kc = 0; kc < 2; ++kc) {
            f16x8 af = *(const f16x8*)&h2s[((wave << 5) + (t2 << 4) + ln) * LSH2 + kc * 32 + quad * 8];
            acc3[t2] = __builtin_amdgcn_mfma_f32_16x16x32_f16(af, bfr[kc], acc3[t2], 0, 0, 0);
        }

#pragma unroll
    for (int t2 = 0; t2 < 2; ++t2)
#pragma unroll
        for (int i = 0; i < 4; ++i) {
            float v = fmaxf(acc3[t2][i] + blv, 0.0f) * wlv;
            v += __shfl_xor(v, 1);
            v += __shfl_xor(v, 2);
            v += __shfl_xor(v, 4);
            v += __shfl_xor(v, 8);
            if (ln == 0) {
                const int row = r0 + (wave << 5) + (t2 << 4) + (quad << 2) + i;
                if (row < N_ROWS) out[row] = v + bl2v;
            }
        }
}

// ---------- launch ----------
extern "C" void kernel_launch(void* const* d_in, const int* in_sizes, int n_in,
                              void* d_out, int out_size, void* d_ws, size_t ws_size,
                              hipStream_t stream) {
    const float* x   = (const float*)d_in[0];
    const float* wz1 = (const float*)d_in[3];
    const float* bz1 = (const float*)d_in[4];
    const float* wh1 = (const float*)d_in[7];
    const float* bh1 = (const float*)d_in[8];
    const float* wz2 = (const float*)d_in[9];
    const float* bz2 = (const float*)d_in[10];
    const float* wh2 = (const float*)d_in[13];
    const float* bh2 = (const float*)d_in[14];
    const float* wl1 = (const float*)d_in[15];
    const float* bl1 = (const float*)d_in[16];
    const float* wl2 = (const float*)d_in[17];
    const float* bl2 = (const float*)d_in[18];

    char* ws = (char*)d_ws;
    f16* W1T = (f16*)(ws + W1T_OFF);
    f16* W2T = (f16*)(ws + W2T_OFF);
    float* out = (float*)d_out;

    prep_w1<<<256, 256, 0, stream>>>(wz1, wh1, W1T);
    prep_w2<<<64, 256, 0, stream>>>(wz2, wh2, W2T);
    fused<<<RT, 256, 0, stream>>>(x, W1T, W2T, bz1, bh1, bz2, bh2,
                                  wl1, bl1, wl2, bl2, out);
}